// Round 1
// baseline (1177.417 us; speedup 1.0000x reference)
//
#include <hip/hip_runtime.h>
#include <math.h>

// Problem constants (fixed by the reference setup_inputs)
constexpr int NH = 8;     // heads
constexpr int D = 32;     // head dim (c/nh)
constexpr int C = 256;    // channels
constexpr int H0 = 128;
constexpr int W0 = 128;
constexpr int LBLK = 4096;  // (H0/2)*(W0/2)
constexpr int K4 = 32;      // 4*k candidates
constexpr int KST = 258;    // LDS row stride for gathered K/V (pad: float2-aligned, 2-way banks)

__global__ __launch_bounds__(256) void cascade_attn_kernel(
    const float* __restrict__ query,   // [2,256,128,128]
    const float* __restrict__ key,
    const float* __restrict__ value,
    const int* __restrict__ topk,      // [2,4096,8,2] int32
    const float* __restrict__ relp,    // [2,8,128,128,32]
    float* __restrict__ out_msg,       // [2,16384,256]
    float* __restrict__ out_idx)       // [2,16384,32] (written as float values)
{
  __shared__ float kv[K4 * KST];      // gathered K, then reused for V  (33 KB)
  __shared__ float qs[4 * C];         // q for the 4 pixels of this block (4 KB)
  __shared__ float as_[NH * K4 * 4];  // softmax probs, layout [h][m][t] (4 KB)

  const int tid = threadIdx.x;
  const int bid = blockIdx.x;
  const int b = bid >> 12;            // / 4096
  const int l = bid & (LBLK - 1);
  const int by = l >> 6, bx = l & 63;
  const int r0 = by * 2, c0 = bx * 2; // top-left pixel of the 2x2 block

  const size_t plane = (size_t)H0 * W0;
  const float* qb = query + (size_t)b * C * plane;
  const float* kb = key   + (size_t)b * C * plane;
  const float* vb = value + (size_t)b * C * plane;
  const int* tp = topk + ((size_t)b * LBLK + l) * 16;  // 8 positions x 2

  // ---- stage q: thread = channel; float2 covers the 2 cols of a row ----
  {
    const float* qp = qb + (size_t)tid * plane + r0 * W0 + c0;
    float2 a  = *(const float2*)qp;          // row r0:  t=0 (c0), t=1 (c0+1)
    float2 bb = *(const float2*)(qp + W0);   // row r0+1: t=2, t=3
    qs[0 * C + tid] = a.x;
    qs[1 * C + tid] = a.y;
    qs[2 * C + tid] = bb.x;
    qs[3 * C + tid] = bb.y;
  }

  // ---- stage gathered K: 16 iters over (jj in 8, x in 2); float2 covers y=0,1 ----
  // topk values in [0,64) -> raw index <= 127*128+127 = 16383: reference clip is a no-op.
#pragma unroll
  for (int it = 0; it < 16; ++it) {
    const int jj = it >> 1, x = it & 1;
    const int pr = tp[jj * 2] * 2 + x;
    const int pc = tp[jj * 2 + 1] * 2;
    float2 f = *(const float2*)(kb + (size_t)tid * plane + pr * W0 + pc);
    const int m0 = jj * 4 + x * 2;           // offs order (0,0),(0,1),(1,0),(1,1)
    kv[m0 * KST + tid] = f.x;
    kv[(m0 + 1) * KST + tid] = f.y;
  }

  // ---- up_idx output: 4 pixels x 32 m per block, same values per pixel ----
  if (tid < 128) {
    const int m = tid & 31, t = tid >> 5;
    const int jj = m >> 2, o = m & 3;
    const int pix = (tp[jj * 2] * 2 + (o >> 1)) * W0 + tp[jj * 2 + 1] * 2 + (o & 1);
    const int prow = r0 + (t >> 1), pcol = c0 + (t & 1);
    out_idx[((size_t)b * plane + prow * W0 + pcol) * K4 + m] = (float)pix;
  }
  __syncthreads();

  const int h = tid >> 5;   // head
  const int m = tid & 31;   // candidate (QK phase) / head-dim lane (PV phase)

  // ---- QK: s[t] = q[t,h,:] . K[m,h,:] ----
  float a0 = 0.f, a1 = 0.f, a2 = 0.f, a3 = 0.f;
#pragma unroll
  for (int dq = 0; dq < 8; ++dq) {
    const int off = h * D + dq * 4;
    float4 q0 = *(const float4*)&qs[0 * C + off];
    float4 q1 = *(const float4*)&qs[1 * C + off];
    float4 q2 = *(const float4*)&qs[2 * C + off];
    float4 q3 = *(const float4*)&qs[3 * C + off];
    float2 ka = *(const float2*)&kv[m * KST + off];
    float2 kc = *(const float2*)&kv[m * KST + off + 2];
    a0 += q0.x * ka.x + q0.y * ka.y + q0.z * kc.x + q0.w * kc.y;
    a1 += q1.x * ka.x + q1.y * ka.y + q1.z * kc.x + q1.w * kc.y;
    a2 += q2.x * ka.x + q2.y * ka.y + q2.z * kc.x + q2.w * kc.y;
    a3 += q3.x * ka.x + q3.y * ka.y + q3.z * kc.x + q3.w * kc.y;
  }

  const float scale = 0.17677669529663687f;  // 1/sqrt(32)
  // rel_pos[b,h,row,col,m]; t=0:(r0,c0) t=1:(r0,c0+1) t=2:(r0+1,c0) t=3:(r0+1,c0+1)
  const size_t rb = ((((size_t)b * NH + h) * H0 + r0) * W0 + c0) * K4 + m;
  float sv[4];
  sv[0] = a0 * scale + relp[rb];
  sv[1] = a1 * scale + relp[rb + K4];
  sv[2] = a2 * scale + relp[rb + (size_t)W0 * K4];
  sv[3] = a3 * scale + relp[rb + (size_t)W0 * K4 + K4];

  // ---- softmax over m (32 lanes; xor masks stay within the m-group) ----
  float pr4[4];
#pragma unroll
  for (int t = 0; t < 4; ++t) {
    float x = sv[t];
    float mx = x;
#pragma unroll
    for (int o = 16; o > 0; o >>= 1) mx = fmaxf(mx, __shfl_xor(mx, o));
    float p = __expf(x - mx);
    float sm = p;
#pragma unroll
    for (int o = 16; o > 0; o >>= 1) sm += __shfl_xor(sm, o);
    pr4[t] = p / sm;
  }
  *(float4*)&as_[tid * 4] = make_float4(pr4[0], pr4[1], pr4[2], pr4[3]);
  __syncthreads();

  // ---- stage gathered V (overwrite kv) ----
#pragma unroll
  for (int it = 0; it < 16; ++it) {
    const int jj = it >> 1, x = it & 1;
    const int pr = tp[jj * 2] * 2 + x;
    const int pc = tp[jj * 2 + 1] * 2;
    float2 f = *(const float2*)(vb + (size_t)tid * plane + pr * W0 + pc);
    const int m0 = jj * 4 + x * 2;
    kv[m0 * KST + tid] = f.x;
    kv[(m0 + 1) * KST + tid] = f.y;
  }
  __syncthreads();

  // ---- PV: out[t,h,j] = sum_m A[t,h,m] * V[m,h,j];  this thread: j = m lane ----
  float o0 = 0.f, o1 = 0.f, o2 = 0.f, o3 = 0.f;
#pragma unroll
  for (int mm = 0; mm < 32; ++mm) {
    float4 a4 = *(const float4*)&as_[(h * K4 + mm) * 4];  // broadcast across j
    float vv = kv[mm * KST + h * D + m];
    o0 += a4.x * vv;
    o1 += a4.y * vv;
    o2 += a4.z * vv;
    o3 += a4.w * vv;
  }
  // out_msg[b, pixel, h*32+j]; consecutive j lanes -> contiguous 128B stores
  const size_t ob = ((size_t)b * plane + (size_t)r0 * W0 + c0) * C + h * D + m;
  out_msg[ob] = o0;
  out_msg[ob + C] = o1;                    // (r0, c0+1)
  out_msg[ob + (size_t)W0 * C] = o2;       // (r0+1, c0)
  out_msg[ob + (size_t)W0 * C + C] = o3;   // (r0+1, c0+1)
}

extern "C" void kernel_launch(void* const* d_in, const int* in_sizes, int n_in,
                              void* d_out, int out_size, void* d_ws, size_t ws_size,
                              hipStream_t stream) {
  const float* q  = (const float*)d_in[0];
  const float* k  = (const float*)d_in[1];
  const float* v  = (const float*)d_in[2];
  const int*   tp = (const int*)d_in[3];
  const float* rp = (const float*)d_in[4];

  float* out_msg = (float*)d_out;
  float* out_idx = out_msg + (size_t)2 * H0 * W0 * C;  // msg first, then up_idx

  dim3 grid(2 * LBLK);
  dim3 block(256);
  hipLaunchKernelGGL(cascade_attn_kernel, grid, block, 0, stream,
                     q, k, v, tp, rp, out_msg, out_idx);
}

// Round 2
// 247.656 us; speedup vs baseline: 4.7542x; 4.7542x over previous
//
#include <hip/hip_runtime.h>
#include <math.h>

// Problem constants (fixed by the reference setup_inputs)
constexpr int NH = 8;     // heads
constexpr int D = 32;     // head dim (c/nh)
constexpr int C = 256;    // channels
constexpr int H0 = 128;
constexpr int W0 = 128;
constexpr int PIX = H0 * W0;   // 16384
constexpr int LBLK = 4096;     // (H0/2)*(W0/2)
constexpr int K4 = 32;         // 4*k candidates
constexpr int KST = 258;       // LDS row stride for gathered K/V (2-way banks = free)

// ---------------------------------------------------------------------------
// Pass 1: transpose q/k/v from [b, C, PIX] to [b, PIX, C] into workspace.
// 64x64 tiles, 256 threads, LDS 64x65 to kill bank conflicts.
// grid = (PIX/64, C/64, 6)  z: array(0=q,1=k,2=v)*2 + b
// ---------------------------------------------------------------------------
__global__ __launch_bounds__(256) void transpose_qkv_kernel(
    const float* __restrict__ q, const float* __restrict__ k,
    const float* __restrict__ v, float* __restrict__ ws)
{
  __shared__ float tile[64][65];
  const int arr = blockIdx.z >> 1;
  const int b = blockIdx.z & 1;
  const float* src = (arr == 0 ? q : arr == 1 ? k : v) + (size_t)b * C * PIX;
  float* dst = ws + (size_t)arr * 2 * PIX * C + (size_t)b * PIX * C;

  const int p0 = blockIdx.x * 64;
  const int c0 = blockIdx.y * 64;
  const int tx = threadIdx.x & 63;
  const int ty = threadIdx.x >> 6;

#pragma unroll
  for (int r = 0; r < 16; ++r) {
    const int ch = ty + r * 4;
    tile[ch][tx] = src[(size_t)(c0 + ch) * PIX + p0 + tx];
  }
  __syncthreads();
#pragma unroll
  for (int r = 0; r < 16; ++r) {
    const int prow = ty + r * 4;
    dst[(size_t)(p0 + prow) * C + c0 + tx] = tile[tx][prow];
  }
}

// ---------------------------------------------------------------------------
// Pass 2: attention. One block per (b, l). Reads q/k/v from the transposed
// [b, PIX, C] layout -> all staging loads fully coalesced.
// ---------------------------------------------------------------------------
__global__ __launch_bounds__(256) void cascade_attn_kernel(
    const float* __restrict__ qT,      // [2, PIX, C]
    const float* __restrict__ kT,
    const float* __restrict__ vT,
    const int* __restrict__ topk,      // [2,4096,8,2] int32
    const float* __restrict__ relp,    // [2,8,128,128,32]
    float* __restrict__ out_msg,       // [2,16384,256]
    float* __restrict__ out_idx)       // [2,16384,32] (float values)
{
  __shared__ float kv[K4 * KST];      // gathered K, then reused for V  (33 KB)
  __shared__ float qs[4 * C];         // q for the 4 pixels of this block (4 KB)
  __shared__ float as_[NH * K4 * 4];  // softmax probs, layout [h][m][t] (4 KB)

  const int tid = threadIdx.x;
  const int bid = blockIdx.x;
  const int b = bid >> 12;
  const int l = bid & (LBLK - 1);
  const int by = l >> 6, bx = l & 63;
  const int r0 = by * 2, c0 = bx * 2;

  const int* tp = topk + ((size_t)b * LBLK + l) * 16;

  // ---- stage q: 4 pixels x 256 contiguous floats; 1 float4/thread ----
  {
    const int t = tid >> 6, ln = tid & 63;
    const int pix = r0 * W0 + c0 + (t >> 1) * W0 + (t & 1);
    float4 f = *(const float4*)&qT[((size_t)b * PIX + pix) * C + ln * 4];
    *(float4*)&qs[t * C + ln * 4] = f;
  }

  // ---- candidate pixel for this thread's gather slice ----
  const int p = tid >> 3;        // candidate m 0..31
  const int ln8 = tid & 7;
  const int jj = p >> 2, o = p & 3;
  const int gpix = (tp[jj * 2] * 2 + (o >> 1)) * W0 + tp[jj * 2 + 1] * 2 + (o & 1);

  // ---- stage gathered K: 8 float4/thread, contiguous per candidate ----
  {
    const float* src = &kT[((size_t)b * PIX + gpix) * C + ln8 * 4];
#pragma unroll
    for (int i = 0; i < 8; ++i) {
      float4 f = *(const float4*)(src + i * 32);
      float* dst = &kv[p * KST + ln8 * 4 + i * 32];
      ((float2*)dst)[0] = make_float2(f.x, f.y);   // KST=258: only 8B-aligned
      ((float2*)(dst + 2))[0] = make_float2(f.z, f.w);
    }
  }

  // ---- prefetch gathered V into registers (hides behind QK/softmax) ----
  float4 vreg[8];
  {
    const float* src = &vT[((size_t)b * PIX + gpix) * C + ln8 * 4];
#pragma unroll
    for (int i = 0; i < 8; ++i) vreg[i] = *(const float4*)(src + i * 32);
  }

  // ---- up_idx output: 4 pixels x 32 m per block ----
  if (tid < 128) {
    const int m = tid & 31, t = tid >> 5;
    const int j2 = m >> 2, o2 = m & 3;
    const int pix = (tp[j2 * 2] * 2 + (o2 >> 1)) * W0 + tp[j2 * 2 + 1] * 2 + (o2 & 1);
    const int prow = r0 + (t >> 1), pcol = c0 + (t & 1);
    out_idx[((size_t)b * PIX + prow * W0 + pcol) * K4 + m] = (float)pix;
  }
  __syncthreads();

  const int h = tid >> 5;   // head
  const int m = tid & 31;   // candidate (QK) / head-dim lane (PV)

  // ---- QK: s[t] = q[t,h,:] . K[m,h,:] ----
  float a0 = 0.f, a1 = 0.f, a2 = 0.f, a3 = 0.f;
#pragma unroll
  for (int dq = 0; dq < 8; ++dq) {
    const int off = h * D + dq * 4;
    float4 q0 = *(const float4*)&qs[0 * C + off];
    float4 q1 = *(const float4*)&qs[1 * C + off];
    float4 q2 = *(const float4*)&qs[2 * C + off];
    float4 q3 = *(const float4*)&qs[3 * C + off];
    float2 ka = *(const float2*)&kv[m * KST + off];
    float2 kc = *(const float2*)&kv[m * KST + off + 2];
    a0 += q0.x * ka.x + q0.y * ka.y + q0.z * kc.x + q0.w * kc.y;
    a1 += q1.x * ka.x + q1.y * ka.y + q1.z * kc.x + q1.w * kc.y;
    a2 += q2.x * ka.x + q2.y * ka.y + q2.z * kc.x + q2.w * kc.y;
    a3 += q3.x * ka.x + q3.y * ka.y + q3.z * kc.x + q3.w * kc.y;
  }

  const float scale = 0.17677669529663687f;  // 1/sqrt(32)
  const size_t rb = ((((size_t)b * NH + h) * H0 + r0) * W0 + c0) * K4 + m;
  float sv[4];
  sv[0] = a0 * scale + relp[rb];
  sv[1] = a1 * scale + relp[rb + K4];
  sv[2] = a2 * scale + relp[rb + (size_t)W0 * K4];
  sv[3] = a3 * scale + relp[rb + (size_t)W0 * K4 + K4];

  // ---- softmax over m (32-lane xor shuffles stay inside the m group) ----
  float pr4[4];
#pragma unroll
  for (int t = 0; t < 4; ++t) {
    float x = sv[t];
    float mx = x;
#pragma unroll
    for (int off = 16; off > 0; off >>= 1) mx = fmaxf(mx, __shfl_xor(mx, off));
    float pbit = __expf(x - mx);
    float sm = pbit;
#pragma unroll
    for (int off = 16; off > 0; off >>= 1) sm += __shfl_xor(sm, off);
    pr4[t] = pbit / sm;
  }
  *(float4*)&as_[tid * 4] = make_float4(pr4[0], pr4[1], pr4[2], pr4[3]);
  __syncthreads();

  // ---- write prefetched V into kv (overwrite K) ----
#pragma unroll
  for (int i = 0; i < 8; ++i) {
    float* dst = &kv[p * KST + ln8 * 4 + i * 32];
    ((float2*)dst)[0] = make_float2(vreg[i].x, vreg[i].y);
    ((float2*)(dst + 2))[0] = make_float2(vreg[i].z, vreg[i].w);
  }
  __syncthreads();

  // ---- PV: out[t,h,j] = sum_m A[t,h,m] * V[m,h,j] ----
  float o0 = 0.f, o1 = 0.f, o2 = 0.f, o3 = 0.f;
#pragma unroll
  for (int mm = 0; mm < 32; ++mm) {
    float4 a4 = *(const float4*)&as_[(h * K4 + mm) * 4];  // broadcast per h-group
    float vv = kv[mm * KST + h * D + m];
    o0 += a4.x * vv;
    o1 += a4.y * vv;
    o2 += a4.z * vv;
    o3 += a4.w * vv;
  }
  const size_t ob = ((size_t)b * PIX + (size_t)r0 * W0 + c0) * C + h * D + m;
  out_msg[ob] = o0;
  out_msg[ob + C] = o1;
  out_msg[ob + (size_t)W0 * C] = o2;
  out_msg[ob + (size_t)W0 * C + C] = o3;
}

// ---------------------------------------------------------------------------
// Fallback (Round-1 kernel, known correct): used only if ws too small.
// ---------------------------------------------------------------------------
__global__ __launch_bounds__(256) void cascade_attn_fallback(
    const float* __restrict__ query, const float* __restrict__ key,
    const float* __restrict__ value, const int* __restrict__ topk,
    const float* __restrict__ relp, float* __restrict__ out_msg,
    float* __restrict__ out_idx)
{
  __shared__ float kv[K4 * KST];
  __shared__ float qs[4 * C];
  __shared__ float as_[NH * K4 * 4];

  const int tid = threadIdx.x;
  const int bid = blockIdx.x;
  const int b = bid >> 12;
  const int l = bid & (LBLK - 1);
  const int by = l >> 6, bx = l & 63;
  const int r0 = by * 2, c0 = bx * 2;

  const size_t plane = (size_t)PIX;
  const float* qb = query + (size_t)b * C * plane;
  const float* kb = key + (size_t)b * C * plane;
  const float* vb = value + (size_t)b * C * plane;
  const int* tp = topk + ((size_t)b * LBLK + l) * 16;

  {
    const float* qp = qb + (size_t)tid * plane + r0 * W0 + c0;
    float2 a = *(const float2*)qp;
    float2 bb = *(const float2*)(qp + W0);
    qs[0 * C + tid] = a.x; qs[1 * C + tid] = a.y;
    qs[2 * C + tid] = bb.x; qs[3 * C + tid] = bb.y;
  }
#pragma unroll
  for (int it = 0; it < 16; ++it) {
    const int jj = it >> 1, x = it & 1;
    const int pr = tp[jj * 2] * 2 + x;
    const int pc = tp[jj * 2 + 1] * 2;
    float2 f = *(const float2*)(kb + (size_t)tid * plane + pr * W0 + pc);
    const int m0 = jj * 4 + x * 2;
    kv[m0 * KST + tid] = f.x;
    kv[(m0 + 1) * KST + tid] = f.y;
  }
  if (tid < 128) {
    const int m = tid & 31, t = tid >> 5;
    const int jj = m >> 2, o = m & 3;
    const int pix = (tp[jj * 2] * 2 + (o >> 1)) * W0 + tp[jj * 2 + 1] * 2 + (o & 1);
    const int prow = r0 + (t >> 1), pcol = c0 + (t & 1);
    out_idx[((size_t)b * plane + prow * W0 + pcol) * K4 + m] = (float)pix;
  }
  __syncthreads();

  const int h = tid >> 5;
  const int m = tid & 31;
  float a0 = 0.f, a1 = 0.f, a2 = 0.f, a3 = 0.f;
#pragma unroll
  for (int dq = 0; dq < 8; ++dq) {
    const int off = h * D + dq * 4;
    float4 q0 = *(const float4*)&qs[0 * C + off];
    float4 q1 = *(const float4*)&qs[1 * C + off];
    float4 q2 = *(const float4*)&qs[2 * C + off];
    float4 q3 = *(const float4*)&qs[3 * C + off];
    float2 ka = *(const float2*)&kv[m * KST + off];
    float2 kc = *(const float2*)&kv[m * KST + off + 2];
    a0 += q0.x * ka.x + q0.y * ka.y + q0.z * kc.x + q0.w * kc.y;
    a1 += q1.x * ka.x + q1.y * ka.y + q1.z * kc.x + q1.w * kc.y;
    a2 += q2.x * ka.x + q2.y * ka.y + q2.z * kc.x + q2.w * kc.y;
    a3 += q3.x * ka.x + q3.y * ka.y + q3.z * kc.x + q3.w * kc.y;
  }
  const float scale = 0.17677669529663687f;
  const size_t rb = ((((size_t)b * NH + h) * H0 + r0) * W0 + c0) * K4 + m;
  float sv[4];
  sv[0] = a0 * scale + relp[rb];
  sv[1] = a1 * scale + relp[rb + K4];
  sv[2] = a2 * scale + relp[rb + (size_t)W0 * K4];
  sv[3] = a3 * scale + relp[rb + (size_t)W0 * K4 + K4];
  float pr4[4];
#pragma unroll
  for (int t = 0; t < 4; ++t) {
    float x = sv[t];
    float mx = x;
#pragma unroll
    for (int off = 16; off > 0; off >>= 1) mx = fmaxf(mx, __shfl_xor(mx, off));
    float pbit = __expf(x - mx);
    float sm = pbit;
#pragma unroll
    for (int off = 16; off > 0; off >>= 1) sm += __shfl_xor(sm, off);
    pr4[t] = pbit / sm;
  }
  *(float4*)&as_[tid * 4] = make_float4(pr4[0], pr4[1], pr4[2], pr4[3]);
  __syncthreads();
#pragma unroll
  for (int it = 0; it < 16; ++it) {
    const int jj = it >> 1, x = it & 1;
    const int pr = tp[jj * 2] * 2 + x;
    const int pc = tp[jj * 2 + 1] * 2;
    float2 f = *(const float2*)(vb + (size_t)tid * plane + pr * W0 + pc);
    const int m0 = jj * 4 + x * 2;
    kv[m0 * KST + tid] = f.x;
    kv[(m0 + 1) * KST + tid] = f.y;
  }
  __syncthreads();
  float o0 = 0.f, o1 = 0.f, o2 = 0.f, o3 = 0.f;
#pragma unroll
  for (int mm = 0; mm < 32; ++mm) {
    float4 a4 = *(const float4*)&as_[(h * K4 + mm) * 4];
    float vv = kv[mm * KST + h * D + m];
    o0 += a4.x * vv; o1 += a4.y * vv; o2 += a4.z * vv; o3 += a4.w * vv;
  }
  const size_t ob = ((size_t)b * plane + (size_t)r0 * W0 + c0) * C + h * D + m;
  out_msg[ob] = o0;
  out_msg[ob + C] = o1;
  out_msg[ob + (size_t)W0 * C] = o2;
  out_msg[ob + (size_t)W0 * C + C] = o3;
}

extern "C" void kernel_launch(void* const* d_in, const int* in_sizes, int n_in,
                              void* d_out, int out_size, void* d_ws, size_t ws_size,
                              hipStream_t stream) {
  const float* q = (const float*)d_in[0];
  const float* k = (const float*)d_in[1];
  const float* v = (const float*)d_in[2];
  const int* tp = (const int*)d_in[3];
  const float* rp = (const float*)d_in[4];

  float* out_msg = (float*)d_out;
  float* out_idx = out_msg + (size_t)2 * PIX * C;

  const size_t needed = (size_t)3 * 2 * PIX * C * sizeof(float);  // 100.7 MB
  if (ws_size >= needed) {
    float* ws = (float*)d_ws;
    float* qT = ws;
    float* kT = ws + (size_t)2 * PIX * C;
    float* vT = ws + (size_t)4 * PIX * C;
    dim3 tg(PIX / 64, C / 64, 6);
    hipLaunchKernelGGL(transpose_qkv_kernel, tg, dim3(256), 0, stream, q, k, v, ws);
    hipLaunchKernelGGL(cascade_attn_kernel, dim3(2 * LBLK), dim3(256), 0, stream,
                       qT, kT, vT, tp, rp, out_msg, out_idx);
  } else {
    hipLaunchKernelGGL(cascade_attn_fallback, dim3(2 * LBLK), dim3(256), 0, stream,
                       q, k, v, tp, rp, out_msg, out_idx);
  }
}

// Round 3
// 240.874 us; speedup vs baseline: 4.8881x; 1.0282x over previous
//
#include <hip/hip_runtime.h>
#include <math.h>

// Problem constants (fixed by the reference setup_inputs)
constexpr int NH = 8;     // heads
constexpr int D = 32;     // head dim (c/nh)
constexpr int C = 256;    // channels
constexpr int H0 = 128;
constexpr int W0 = 128;
constexpr int PIX = H0 * W0;   // 16384
constexpr int LBLK = 4096;     // (H0/2)*(W0/2)
constexpr int K4 = 32;         // 4*k candidates
constexpr int KST = 258;       // LDS row stride for gathered K/V (2-way banks = free)

// ---------------------------------------------------------------------------
// Pass 1: transpose q/k/v from [b, C, PIX] to [b, PIX, C] into workspace.
// float4 on BOTH global sides; LDS pitch 65 + scalar LDS ops -> <=2-way banks.
// grid = (PIX/64, C/64, 6)  z: array(0=q,1=k,2=v)*2 + b
// ---------------------------------------------------------------------------
__global__ __launch_bounds__(256) void transpose_qkv_kernel(
    const float* __restrict__ q, const float* __restrict__ k,
    const float* __restrict__ v, float* __restrict__ ws)
{
  __shared__ float tile[64 * 65];
  const int arr = blockIdx.z >> 1;
  const int b = blockIdx.z & 1;
  const float* src = (arr == 0 ? q : arr == 1 ? k : v) + (size_t)b * C * PIX;
  float* dst = ws + (size_t)arr * 2 * PIX * C + (size_t)b * PIX * C;

  const int p0 = blockIdx.x * 64;
  const int c0 = blockIdx.y * 64;
  const int t15 = threadIdx.x & 15;   // float4 lane within a row
  const int thi = threadIdx.x >> 4;   // 0..15

#pragma unroll
  for (int r = 0; r < 4; ++r) {
    const int ch = thi + r * 16;       // channel row
    const int p4 = t15 * 4;            // pixel start
    float4 f = *(const float4*)&src[(size_t)(c0 + ch) * PIX + p0 + p4];
    tile[(p4 + 0) * 65 + ch] = f.x;
    tile[(p4 + 1) * 65 + ch] = f.y;
    tile[(p4 + 2) * 65 + ch] = f.z;
    tile[(p4 + 3) * 65 + ch] = f.w;
  }
  __syncthreads();
#pragma unroll
  for (int r = 0; r < 4; ++r) {
    const int p = thi + r * 16;        // pixel row
    const int c4 = t15 * 4;            // channel start
    const float* tr = &tile[p * 65 + c4];
    float4 g = make_float4(tr[0], tr[1], tr[2], tr[3]);
    *(float4*)&dst[(size_t)(p0 + p) * C + c0 + c4] = g;
  }
}

// ---------------------------------------------------------------------------
// Pass 2: attention. One block per (b, l). q/k/v read from [b, PIX, C].
// LDS: kv (33 KB, K then V) + qa (4 KB, q during QK, softmax probs after).
// 37.1 KB -> 4 blocks/CU.
// ---------------------------------------------------------------------------
__global__ __launch_bounds__(256) void cascade_attn_kernel(
    const float* __restrict__ qT,      // [2, PIX, C]
    const float* __restrict__ kT,
    const float* __restrict__ vT,
    const int* __restrict__ topk,      // [2,4096,8,2] int32
    const float* __restrict__ relp,    // [2,8,128,128,32]
    float* __restrict__ out_msg,       // [2,16384,256]
    float* __restrict__ out_idx)       // [2,16384,32] (float values)
{
  __shared__ float kv[K4 * KST];      // gathered K, then reused for V (33,024 B)
  __shared__ float qa[4 * C];         // q for 4 pixels; after QK: probs [h][m][t]

  const int tid = threadIdx.x;
  const int bid = blockIdx.x;
  const int b = bid >> 12;
  const int l = bid & (LBLK - 1);
  const int by = l >> 6, bx = l & 63;
  const int r0 = by * 2, c0 = bx * 2;

  const int* tp = topk + ((size_t)b * LBLK + l) * 16;

  const int h = tid >> 5;   // head
  const int m = tid & 31;   // candidate (QK) / head-dim lane (PV)

  // ---- stage q: 4 pixels x 256 contiguous floats; 1 float4/thread ----
  {
    const int t = tid >> 6, ln = tid & 63;
    const int pix = r0 * W0 + c0 + (t >> 1) * W0 + (t & 1);
    float4 f = *(const float4*)&qT[((size_t)b * PIX + pix) * C + ln * 4];
    *(float4*)&qa[t * C + ln * 4] = f;
  }

  // ---- candidate pixel for this thread's gather slice ----
  const int p = tid >> 3;        // candidate m 0..31
  const int ln8 = tid & 7;
  const int jj = p >> 2, o = p & 3;
  const int gpix = (tp[jj * 2] * 2 + (o >> 1)) * W0 + tp[jj * 2 + 1] * 2 + (o & 1);

  // ---- stage gathered K: 8 float4/thread, contiguous per candidate ----
  {
    const float* src = &kT[((size_t)b * PIX + gpix) * C + ln8 * 4];
#pragma unroll
    for (int i = 0; i < 8; ++i) {
      float4 f = *(const float4*)(src + i * 32);
      float* dst = &kv[p * KST + ln8 * 4 + i * 32];
      ((float2*)dst)[0] = make_float2(f.x, f.y);   // KST=258: 8B-aligned only
      ((float2*)(dst + 2))[0] = make_float2(f.z, f.w);
    }
  }

  // ---- prefetch gathered V into registers (latency hides behind QK) ----
  float4 vreg[8];
  {
    const float* src = &vT[((size_t)b * PIX + gpix) * C + ln8 * 4];
#pragma unroll
    for (int i = 0; i < 8; ++i) vreg[i] = *(const float4*)(src + i * 32);
  }

  // ---- prefetch rel_pos for this (h,m): 4 floats, coalesced over m ----
  const size_t rb = ((((size_t)b * NH + h) * H0 + r0) * W0 + c0) * K4 + m;
  float rl0 = relp[rb];
  float rl1 = relp[rb + K4];
  float rl2 = relp[rb + (size_t)W0 * K4];
  float rl3 = relp[rb + (size_t)W0 * K4 + K4];

  // ---- up_idx output: 4 pixels x 32 m per block ----
  if (tid < 128) {
    const int mm = tid & 31, t = tid >> 5;
    const int j2 = mm >> 2, o2 = mm & 3;
    const int pix = (tp[j2 * 2] * 2 + (o2 >> 1)) * W0 + tp[j2 * 2 + 1] * 2 + (o2 & 1);
    const int prow = r0 + (t >> 1), pcol = c0 + (t & 1);
    out_idx[((size_t)b * PIX + prow * W0 + pcol) * K4 + mm] = (float)pix;
  }
  __syncthreads();   // (1) staging visible

  // ---- QK: s[t] = q[t,h,:] . K[m,h,:] ----
  float a0 = 0.f, a1 = 0.f, a2 = 0.f, a3 = 0.f;
#pragma unroll
  for (int dq = 0; dq < 8; ++dq) {
    const int off = h * D + dq * 4;
    float4 q0 = *(const float4*)&qa[0 * C + off];
    float4 q1 = *(const float4*)&qa[1 * C + off];
    float4 q2 = *(const float4*)&qa[2 * C + off];
    float4 q3 = *(const float4*)&qa[3 * C + off];
    float2 ka = *(const float2*)&kv[m * KST + off];
    float2 kc = *(const float2*)&kv[m * KST + off + 2];
    a0 += q0.x * ka.x + q0.y * ka.y + q0.z * kc.x + q0.w * kc.y;
    a1 += q1.x * ka.x + q1.y * ka.y + q1.z * kc.x + q1.w * kc.y;
    a2 += q2.x * ka.x + q2.y * ka.y + q2.z * kc.x + q2.w * kc.y;
    a3 += q3.x * ka.x + q3.y * ka.y + q3.z * kc.x + q3.w * kc.y;
  }

  const float scale = 0.17677669529663687f;  // 1/sqrt(32)
  float sv[4];
  sv[0] = a0 * scale + rl0;
  sv[1] = a1 * scale + rl1;
  sv[2] = a2 * scale + rl2;
  sv[3] = a3 * scale + rl3;

  // ---- softmax over m (32-lane xor shuffles stay inside the m group) ----
  float pr4[4];
#pragma unroll
  for (int t = 0; t < 4; ++t) {
    float x = sv[t];
    float mx = x;
#pragma unroll
    for (int off = 16; off > 0; off >>= 1) mx = fmaxf(mx, __shfl_xor(mx, off));
    float pbit = __expf(x - mx);
    float sm = pbit;
#pragma unroll
    for (int off = 16; off > 0; off >>= 1) sm += __shfl_xor(sm, off);
    pr4[t] = pbit / sm;
  }
  __syncthreads();   // (2) all QK reads of qa & kv complete

  // ---- write probs into qa (q is dead) and V into kv (K is dead) ----
  *(float4*)&qa[tid * 4] = make_float4(pr4[0], pr4[1], pr4[2], pr4[3]);
#pragma unroll
  for (int i = 0; i < 8; ++i) {
    float* dst = &kv[p * KST + ln8 * 4 + i * 32];
    ((float2*)dst)[0] = make_float2(vreg[i].x, vreg[i].y);
    ((float2*)(dst + 2))[0] = make_float2(vreg[i].z, vreg[i].w);
  }
  __syncthreads();   // (3) probs + V visible

  // ---- PV: out[t,h,j] = sum_m A[t,h,m] * V[m,h,j] ----
  float o0 = 0.f, o1 = 0.f, o2 = 0.f, o3 = 0.f;
#pragma unroll
  for (int mm = 0; mm < 32; ++mm) {
    float4 a4 = *(const float4*)&qa[(h * K4 + mm) * 4];  // broadcast per h-group
    float vv = kv[mm * KST + h * D + m];
    o0 += a4.x * vv;
    o1 += a4.y * vv;
    o2 += a4.z * vv;
    o3 += a4.w * vv;
  }
  const size_t ob = ((size_t)b * PIX + (size_t)r0 * W0 + c0) * C + h * D + m;
  out_msg[ob] = o0;
  out_msg[ob + C] = o1;
  out_msg[ob + (size_t)W0 * C] = o2;
  out_msg[ob + (size_t)W0 * C + C] = o3;
}

// ---------------------------------------------------------------------------
// Fallback (Round-1 kernel, known correct): used only if ws too small.
// ---------------------------------------------------------------------------
__global__ __launch_bounds__(256) void cascade_attn_fallback(
    const float* __restrict__ query, const float* __restrict__ key,
    const float* __restrict__ value, const int* __restrict__ topk,
    const float* __restrict__ relp, float* __restrict__ out_msg,
    float* __restrict__ out_idx)
{
  __shared__ float kv[K4 * KST];
  __shared__ float qs[4 * C];
  __shared__ float as_[NH * K4 * 4];

  const int tid = threadIdx.x;
  const int bid = blockIdx.x;
  const int b = bid >> 12;
  const int l = bid & (LBLK - 1);
  const int by = l >> 6, bx = l & 63;
  const int r0 = by * 2, c0 = bx * 2;

  const size_t plane = (size_t)PIX;
  const float* qb = query + (size_t)b * C * plane;
  const float* kb = key + (size_t)b * C * plane;
  const float* vb = value + (size_t)b * C * plane;
  const int* tp = topk + ((size_t)b * LBLK + l) * 16;

  {
    const float* qp = qb + (size_t)tid * plane + r0 * W0 + c0;
    float2 a = *(const float2*)qp;
    float2 bb = *(const float2*)(qp + W0);
    qs[0 * C + tid] = a.x; qs[1 * C + tid] = a.y;
    qs[2 * C + tid] = bb.x; qs[3 * C + tid] = bb.y;
  }
#pragma unroll
  for (int it = 0; it < 16; ++it) {
    const int jj = it >> 1, x = it & 1;
    const int pr = tp[jj * 2] * 2 + x;
    const int pc = tp[jj * 2 + 1] * 2;
    float2 f = *(const float2*)(kb + (size_t)tid * plane + pr * W0 + pc);
    const int m0 = jj * 4 + x * 2;
    kv[m0 * KST + tid] = f.x;
    kv[(m0 + 1) * KST + tid] = f.y;
  }
  if (tid < 128) {
    const int m = tid & 31, t = tid >> 5;
    const int jj = m >> 2, o = m & 3;
    const int pix = (tp[jj * 2] * 2 + (o >> 1)) * W0 + tp[jj * 2 + 1] * 2 + (o & 1);
    const int prow = r0 + (t >> 1), pcol = c0 + (t & 1);
    out_idx[((size_t)b * plane + prow * W0 + pcol) * K4 + m] = (float)pix;
  }
  __syncthreads();

  const int h = tid >> 5;
  const int m = tid & 31;
  float a0 = 0.f, a1 = 0.f, a2 = 0.f, a3 = 0.f;
#pragma unroll
  for (int dq = 0; dq < 8; ++dq) {
    const int off = h * D + dq * 4;
    float4 q0 = *(const float4*)&qs[0 * C + off];
    float4 q1 = *(const float4*)&qs[1 * C + off];
    float4 q2 = *(const float4*)&qs[2 * C + off];
    float4 q3 = *(const float4*)&qs[3 * C + off];
    float2 ka = *(const float2*)&kv[m * KST + off];
    float2 kc = *(const float2*)&kv[m * KST + off + 2];
    a0 += q0.x * ka.x + q0.y * ka.y + q0.z * kc.x + q0.w * kc.y;
    a1 += q1.x * ka.x + q1.y * ka.y + q1.z * kc.x + q1.w * kc.y;
    a2 += q2.x * ka.x + q2.y * ka.y + q2.z * kc.x + q2.w * kc.y;
    a3 += q3.x * ka.x + q3.y * ka.y + q3.z * kc.x + q3.w * kc.y;
  }
  const float scale = 0.17677669529663687f;
  const size_t rb = ((((size_t)b * NH + h) * H0 + r0) * W0 + c0) * K4 + m;
  float sv[4];
  sv[0] = a0 * scale + relp[rb];
  sv[1] = a1 * scale + relp[rb + K4];
  sv[2] = a2 * scale + relp[rb + (size_t)W0 * K4];
  sv[3] = a3 * scale + relp[rb + (size_t)W0 * K4 + K4];
  float pr4[4];
#pragma unroll
  for (int t = 0; t < 4; ++t) {
    float x = sv[t];
    float mx = x;
#pragma unroll
    for (int off = 16; off > 0; off >>= 1) mx = fmaxf(mx, __shfl_xor(mx, off));
    float pbit = __expf(x - mx);
    float sm = pbit;
#pragma unroll
    for (int off = 16; off > 0; off >>= 1) sm += __shfl_xor(sm, off);
    pr4[t] = pbit / sm;
  }
  *(float4*)&as_[tid * 4] = make_float4(pr4[0], pr4[1], pr4[2], pr4[3]);
  __syncthreads();
#pragma unroll
  for (int it = 0; it < 16; ++it) {
    const int jj = it >> 1, x = it & 1;
    const int pr = tp[jj * 2] * 2 + x;
    const int pc = tp[jj * 2 + 1] * 2;
    float2 f = *(const float2*)(vb + (size_t)tid * plane + pr * W0 + pc);
    const int m0 = jj * 4 + x * 2;
    kv[m0 * KST + tid] = f.x;
    kv[(m0 + 1) * KST + tid] = f.y;
  }
  __syncthreads();
  float o0 = 0.f, o1 = 0.f, o2 = 0.f, o3 = 0.f;
#pragma unroll
  for (int mm = 0; mm < 32; ++mm) {
    float4 a4 = *(const float4*)&as_[(h * K4 + mm) * 4];
    float vv = kv[mm * KST + h * D + m];
    o0 += a4.x * vv; o1 += a4.y * vv; o2 += a4.z * vv; o3 += a4.w * vv;
  }
  const size_t ob = ((size_t)b * plane + (size_t)r0 * W0 + c0) * C + h * D + m;
  out_msg[ob] = o0;
  out_msg[ob + C] = o1;
  out_msg[ob + (size_t)W0 * C] = o2;
  out_msg[ob + (size_t)W0 * C + C] = o3;
}

extern "C" void kernel_launch(void* const* d_in, const int* in_sizes, int n_in,
                              void* d_out, int out_size, void* d_ws, size_t ws_size,
                              hipStream_t stream) {
  const float* q = (const float*)d_in[0];
  const float* k = (const float*)d_in[1];
  const float* v = (const float*)d_in[2];
  const int* tp = (const int*)d_in[3];
  const float* rp = (const float*)d_in[4];

  float* out_msg = (float*)d_out;
  float* out_idx = out_msg + (size_t)2 * PIX * C;

  const size_t needed = (size_t)3 * 2 * PIX * C * sizeof(float);  // 100.7 MB
  if (ws_size >= needed) {
    float* ws = (float*)d_ws;
    float* qT = ws;
    float* kT = ws + (size_t)2 * PIX * C;
    float* vT = ws + (size_t)4 * PIX * C;
    dim3 tg(PIX / 64, C / 64, 6);
    hipLaunchKernelGGL(transpose_qkv_kernel, tg, dim3(256), 0, stream, q, k, v, ws);
    hipLaunchKernelGGL(cascade_attn_kernel, dim3(2 * LBLK), dim3(256), 0, stream,
                       qT, kT, vT, tp, rp, out_msg, out_idx);
  } else {
    hipLaunchKernelGGL(cascade_attn_fallback, dim3(2 * LBLK), dim3(256), 0, stream,
                       q, k, v, tp, rp, out_msg, out_idx);
  }
}

// Round 4
// 208.932 us; speedup vs baseline: 5.6354x; 1.1529x over previous
//
#include <hip/hip_runtime.h>
#include <hip/hip_fp16.h>
#include <math.h>

// Problem constants (fixed by the reference setup_inputs)
constexpr int NH = 8;     // heads
constexpr int D = 32;     // head dim (c/nh)
constexpr int C = 256;    // channels
constexpr int H0 = 128;
constexpr int W0 = 128;
constexpr int PIX = H0 * W0;   // 16384
constexpr int LBLK = 4096;     // (H0/2)*(W0/2)
constexpr int K4 = 32;         // 4*k candidates
constexpr int KSTH = 260;      // LDS row stride in HALVES (520 B -> 2-bank row shift, 2-way max)
constexpr int KST = 258;       // fp32 fallback stride

// ---------------------------------------------------------------------------
// Pass 1: transpose q/k/v from [b, C, PIX] to [b, PIX, C].
// q -> fp32 qT; k/v -> fp16 kT/vT (halves transpose-write + attention-fetch BW).
// grid = (PIX/64, C/64, 6)  z: 0,1=q(b) 2,3=k(b) 4,5=v(b)
// ---------------------------------------------------------------------------
__global__ __launch_bounds__(256) void transpose_qkv_kernel(
    const float* __restrict__ q, const float* __restrict__ k,
    const float* __restrict__ v, float* __restrict__ qT,
    __half* __restrict__ kT, __half* __restrict__ vT)
{
  __shared__ float tile[64 * 65];
  const int z = blockIdx.z;
  const int b = z & 1;
  const int arr = z >> 1;   // 0=q, 1=k, 2=v
  const float* src = (arr == 0 ? q : arr == 1 ? k : v) + (size_t)b * C * PIX;

  const int p0 = blockIdx.x * 64;
  const int c0 = blockIdx.y * 64;
  const int t15 = threadIdx.x & 15;
  const int thi4 = threadIdx.x >> 4;   // 0..15

#pragma unroll
  for (int r = 0; r < 4; ++r) {
    const int ch = thi4 + r * 16;      // channel row
    const int p4 = t15 * 4;            // pixel start
    float4 f = *(const float4*)&src[(size_t)(c0 + ch) * PIX + p0 + p4];
    tile[(p4 + 0) * 65 + ch] = f.x;
    tile[(p4 + 1) * 65 + ch] = f.y;
    tile[(p4 + 2) * 65 + ch] = f.z;
    tile[(p4 + 3) * 65 + ch] = f.w;
  }
  __syncthreads();

  if (arr == 0) {
    float* dst = qT + (size_t)b * PIX * C;
#pragma unroll
    for (int r = 0; r < 4; ++r) {
      const int p = thi4 + r * 16;
      const int c4 = t15 * 4;
      const float* tr = &tile[p * 65 + c4];
      *(float4*)&dst[(size_t)(p0 + p) * C + c0 + c4] =
          make_float4(tr[0], tr[1], tr[2], tr[3]);
    }
  } else {
    __half* dst = (arr == 1 ? kT : vT) + (size_t)b * PIX * C;
    const int t7 = threadIdx.x & 7;
    const int th8 = threadIdx.x >> 3;  // 0..31
#pragma unroll
    for (int r = 0; r < 2; ++r) {
      const int p = th8 + r * 32;
      const int c8 = t7 * 8;
      const float* tr = &tile[p * 65 + c8];
      __half2 h0 = __floats2half2_rn(tr[0], tr[1]);
      __half2 h1 = __floats2half2_rn(tr[2], tr[3]);
      __half2 h2 = __floats2half2_rn(tr[4], tr[5]);
      __half2 h3 = __floats2half2_rn(tr[6], tr[7]);
      uint4 u;
      u.x = *(unsigned*)&h0; u.y = *(unsigned*)&h1;
      u.z = *(unsigned*)&h2; u.w = *(unsigned*)&h3;
      *(uint4*)&dst[(size_t)(p0 + p) * C + c0 + c8] = u;   // 16B aligned
    }
  }
}

// ---------------------------------------------------------------------------
// Pass 2: attention. One block per (b, l). K/V fp16 in ws and LDS, q fp32.
// LDS: kvh 16,640 B + qa 4,096 B = 20,736 B -> 7 blocks/CU.
// ---------------------------------------------------------------------------
__global__ __launch_bounds__(256) void cascade_attn_f16(
    const float* __restrict__ qT,      // [2, PIX, C] fp32
    const __half* __restrict__ kT,     // [2, PIX, C] fp16
    const __half* __restrict__ vT,
    const int* __restrict__ topk,      // [2,4096,8,2] int32
    const float* __restrict__ relp,    // [2,8,128,128,32] fp32
    float* __restrict__ out_msg,       // [2,16384,256]
    float* __restrict__ out_idx)       // [2,16384,32] (float values)
{
  __shared__ __half kvh[K4 * KSTH];   // gathered K, then V (16,640 B)
  __shared__ float qa[4 * C];         // q during QK; softmax probs after (4 KB)

  const int tid = threadIdx.x;
  const int bid = blockIdx.x;
  const int b = bid >> 12;
  const int l = bid & (LBLK - 1);
  const int by = l >> 6, bx = l & 63;
  const int r0 = by * 2, c0 = bx * 2;

  const int* tp = topk + ((size_t)b * LBLK + l) * 16;

  const int h = tid >> 5;   // head
  const int m = tid & 31;   // candidate (QK) / head-dim lane (PV)

  // ---- stage q: 4 pixels x 256 contiguous floats; 1 float4/thread ----
  {
    const int t = tid >> 6, ln = tid & 63;
    const int pix = r0 * W0 + c0 + (t >> 1) * W0 + (t & 1);
    float4 f = *(const float4*)&qT[((size_t)b * PIX + pix) * C + ln * 4];
    *(float4*)&qa[t * C + ln * 4] = f;
  }

  // ---- candidate pixel for this thread's gather slice ----
  const int p = tid >> 3;        // candidate m 0..31
  const int ln8 = tid & 7;
  const int jj = p >> 2, o = p & 3;
  const int gpix = (tp[jj * 2] * 2 + (o >> 1)) * W0 + tp[jj * 2 + 1] * 2 + (o & 1);

  // ---- stage gathered K: 4 x uint4 (8 halves each) per thread ----
  {
    const __half* src = &kT[((size_t)b * PIX + gpix) * C + ln8 * 8];
#pragma unroll
    for (int i = 0; i < 4; ++i) {
      uint4 f = *(const uint4*)(src + i * 64);      // 16B aligned
      __half* dst = &kvh[p * KSTH + ln8 * 8 + i * 64];
      *(uint2*)dst = make_uint2(f.x, f.y);          // 8B aligned (row = 520 B)
      *(uint2*)(dst + 4) = make_uint2(f.z, f.w);
    }
  }

  // ---- prefetch gathered V into registers (latency hides behind QK) ----
  uint4 vreg[4];
  {
    const __half* src = &vT[((size_t)b * PIX + gpix) * C + ln8 * 8];
#pragma unroll
    for (int i = 0; i < 4; ++i) vreg[i] = *(const uint4*)(src + i * 64);
  }

  // ---- prefetch rel_pos for this (h,m): 4 floats, coalesced over m ----
  const size_t rb = ((((size_t)b * NH + h) * H0 + r0) * W0 + c0) * K4 + m;
  float rl0 = relp[rb];
  float rl1 = relp[rb + K4];
  float rl2 = relp[rb + (size_t)W0 * K4];
  float rl3 = relp[rb + (size_t)W0 * K4 + K4];

  // ---- up_idx output: 4 pixels x 32 m per block ----
  if (tid < 128) {
    const int mm = tid & 31, t = tid >> 5;
    const int j2 = mm >> 2, o2 = mm & 3;
    const int pix = (tp[j2 * 2] * 2 + (o2 >> 1)) * W0 + tp[j2 * 2 + 1] * 2 + (o2 & 1);
    const int prow = r0 + (t >> 1), pcol = c0 + (t & 1);
    out_idx[((size_t)b * PIX + prow * W0 + pcol) * K4 + mm] = (float)pix;
  }
  __syncthreads();   // (1) staging visible

  // ---- QK: s[t] = q[t,h,:] . K[m,h,:] ----
  float a0 = 0.f, a1 = 0.f, a2 = 0.f, a3 = 0.f;
#pragma unroll
  for (int dq = 0; dq < 8; ++dq) {
    const int off = h * D + dq * 4;
    float4 q0 = *(const float4*)&qa[0 * C + off];
    float4 q1 = *(const float4*)&qa[1 * C + off];
    float4 q2 = *(const float4*)&qa[2 * C + off];
    float4 q3 = *(const float4*)&qa[3 * C + off];
    uint2 kraw = *(const uint2*)&kvh[m * KSTH + off];   // 8B aligned, 2-way banks
    __half2 kh0 = *(__half2*)&kraw.x;
    __half2 kh1 = *(__half2*)&kraw.y;
    float2 ka = __half22float2(kh0);
    float2 kc = __half22float2(kh1);
    a0 += q0.x * ka.x + q0.y * ka.y + q0.z * kc.x + q0.w * kc.y;
    a1 += q1.x * ka.x + q1.y * ka.y + q1.z * kc.x + q1.w * kc.y;
    a2 += q2.x * ka.x + q2.y * ka.y + q2.z * kc.x + q2.w * kc.y;
    a3 += q3.x * ka.x + q3.y * ka.y + q3.z * kc.x + q3.w * kc.y;
  }

  const float scale = 0.17677669529663687f;  // 1/sqrt(32)
  float sv[4];
  sv[0] = a0 * scale + rl0;
  sv[1] = a1 * scale + rl1;
  sv[2] = a2 * scale + rl2;
  sv[3] = a3 * scale + rl3;

  // ---- softmax over m (32-lane xor shuffles stay inside the m group) ----
  float pr4[4];
#pragma unroll
  for (int t = 0; t < 4; ++t) {
    float x = sv[t];
    float mx = x;
#pragma unroll
    for (int off = 16; off > 0; off >>= 1) mx = fmaxf(mx, __shfl_xor(mx, off));
    float pbit = __expf(x - mx);
    float sm = pbit;
#pragma unroll
    for (int off = 16; off > 0; off >>= 1) sm += __shfl_xor(sm, off);
    pr4[t] = pbit / sm;
  }
  __syncthreads();   // (2) all QK reads of qa & kvh complete

  // ---- write probs into qa (q dead) and V into kvh (K dead) ----
  *(float4*)&qa[tid * 4] = make_float4(pr4[0], pr4[1], pr4[2], pr4[3]);
#pragma unroll
  for (int i = 0; i < 4; ++i) {
    __half* dst = &kvh[p * KSTH + ln8 * 8 + i * 64];
    *(uint2*)dst = make_uint2(vreg[i].x, vreg[i].y);
    *(uint2*)(dst + 4) = make_uint2(vreg[i].z, vreg[i].w);
  }
  __syncthreads();   // (3) probs + V visible

  // ---- PV: out[t,h,j] = sum_m A[t,h,m] * V[m,h,j] ----
  float o0 = 0.f, o1 = 0.f, o2 = 0.f, o3 = 0.f;
#pragma unroll
  for (int mm = 0; mm < 32; ++mm) {
    float4 a4 = *(const float4*)&qa[(h * K4 + mm) * 4];  // broadcast per h-group
    float vv = __half2float(kvh[mm * KSTH + h * D + m]); // <=2-way banks
    o0 += a4.x * vv;
    o1 += a4.y * vv;
    o2 += a4.z * vv;
    o3 += a4.w * vv;
  }
  const size_t ob = ((size_t)b * PIX + (size_t)r0 * W0 + c0) * C + h * D + m;
  out_msg[ob] = o0;
  out_msg[ob + C] = o1;
  out_msg[ob + (size_t)W0 * C] = o2;
  out_msg[ob + (size_t)W0 * C + C] = o3;
}

// ---------------------------------------------------------------------------
// Fallback (Round-1 kernel, known correct): used only if ws too small.
// ---------------------------------------------------------------------------
__global__ __launch_bounds__(256) void cascade_attn_fallback(
    const float* __restrict__ query, const float* __restrict__ key,
    const float* __restrict__ value, const int* __restrict__ topk,
    const float* __restrict__ relp, float* __restrict__ out_msg,
    float* __restrict__ out_idx)
{
  __shared__ float kv[K4 * KST];
  __shared__ float qs[4 * C];
  __shared__ float as_[NH * K4 * 4];

  const int tid = threadIdx.x;
  const int bid = blockIdx.x;
  const int b = bid >> 12;
  const int l = bid & (LBLK - 1);
  const int by = l >> 6, bx = l & 63;
  const int r0 = by * 2, c0 = bx * 2;

  const size_t plane = (size_t)PIX;
  const float* qb = query + (size_t)b * C * plane;
  const float* kb = key + (size_t)b * C * plane;
  const float* vb = value + (size_t)b * C * plane;
  const int* tp = topk + ((size_t)b * LBLK + l) * 16;

  {
    const float* qp = qb + (size_t)tid * plane + r0 * W0 + c0;
    float2 a = *(const float2*)qp;
    float2 bb = *(const float2*)(qp + W0);
    qs[0 * C + tid] = a.x; qs[1 * C + tid] = a.y;
    qs[2 * C + tid] = bb.x; qs[3 * C + tid] = bb.y;
  }
#pragma unroll
  for (int it = 0; it < 16; ++it) {
    const int jj = it >> 1, x = it & 1;
    const int pr = tp[jj * 2] * 2 + x;
    const int pc = tp[jj * 2 + 1] * 2;
    float2 f = *(const float2*)(kb + (size_t)tid * plane + pr * W0 + pc);
    const int m0 = jj * 4 + x * 2;
    kv[m0 * KST + tid] = f.x;
    kv[(m0 + 1) * KST + tid] = f.y;
  }
  if (tid < 128) {
    const int m = tid & 31, t = tid >> 5;
    const int jj = m >> 2, o = m & 3;
    const int pix = (tp[jj * 2] * 2 + (o >> 1)) * W0 + tp[jj * 2 + 1] * 2 + (o & 1);
    const int prow = r0 + (t >> 1), pcol = c0 + (t & 1);
    out_idx[((size_t)b * plane + prow * W0 + pcol) * K4 + m] = (float)pix;
  }
  __syncthreads();

  const int h = tid >> 5;
  const int m = tid & 31;
  float a0 = 0.f, a1 = 0.f, a2 = 0.f, a3 = 0.f;
#pragma unroll
  for (int dq = 0; dq < 8; ++dq) {
    const int off = h * D + dq * 4;
    float4 q0 = *(const float4*)&qs[0 * C + off];
    float4 q1 = *(const float4*)&qs[1 * C + off];
    float4 q2 = *(const float4*)&qs[2 * C + off];
    float4 q3 = *(const float4*)&qs[3 * C + off];
    float2 ka = *(const float2*)&kv[m * KST + off];
    float2 kc = *(const float2*)&kv[m * KST + off + 2];
    a0 += q0.x * ka.x + q0.y * ka.y + q0.z * kc.x + q0.w * kc.y;
    a1 += q1.x * ka.x + q1.y * ka.y + q1.z * kc.x + q1.w * kc.y;
    a2 += q2.x * ka.x + q2.y * ka.y + q2.z * kc.x + q2.w * kc.y;
    a3 += q3.x * ka.x + q3.y * ka.y + q3.z * kc.x + q3.w * kc.y;
  }
  const float scale = 0.17677669529663687f;
  const size_t rb = ((((size_t)b * NH + h) * H0 + r0) * W0 + c0) * K4 + m;
  float sv[4];
  sv[0] = a0 * scale + relp[rb];
  sv[1] = a1 * scale + relp[rb + K4];
  sv[2] = a2 * scale + relp[rb + (size_t)W0 * K4];
  sv[3] = a3 * scale + relp[rb + (size_t)W0 * K4 + K4];
  float pr4[4];
#pragma unroll
  for (int t = 0; t < 4; ++t) {
    float x = sv[t];
    float mx = x;
#pragma unroll
    for (int off = 16; off > 0; off >>= 1) mx = fmaxf(mx, __shfl_xor(mx, off));
    float pbit = __expf(x - mx);
    float sm = pbit;
#pragma unroll
    for (int off = 16; off > 0; off >>= 1) sm += __shfl_xor(sm, off);
    pr4[t] = pbit / sm;
  }
  *(float4*)&as_[tid * 4] = make_float4(pr4[0], pr4[1], pr4[2], pr4[3]);
  __syncthreads();
#pragma unroll
  for (int it = 0; it < 16; ++it) {
    const int jj = it >> 1, x = it & 1;
    const int pr = tp[jj * 2] * 2 + x;
    const int pc = tp[jj * 2 + 1] * 2;
    float2 f = *(const float2*)(vb + (size_t)tid * plane + pr * W0 + pc);
    const int m0 = jj * 4 + x * 2;
    kv[m0 * KST + tid] = f.x;
    kv[(m0 + 1) * KST + tid] = f.y;
  }
  __syncthreads();
  float o0 = 0.f, o1 = 0.f, o2 = 0.f, o3 = 0.f;
#pragma unroll
  for (int mm = 0; mm < 32; ++mm) {
    float4 a4 = *(const float4*)&as_[(h * K4 + mm) * 4];
    float vv = kv[mm * KST + h * D + m];
    o0 += a4.x * vv; o1 += a4.y * vv; o2 += a4.z * vv; o3 += a4.w * vv;
  }
  const size_t ob = ((size_t)b * plane + (size_t)r0 * W0 + c0) * C + h * D + m;
  out_msg[ob] = o0;
  out_msg[ob + C] = o1;
  out_msg[ob + (size_t)W0 * C] = o2;
  out_msg[ob + (size_t)W0 * C + C] = o3;
}

extern "C" void kernel_launch(void* const* d_in, const int* in_sizes, int n_in,
                              void* d_out, int out_size, void* d_ws, size_t ws_size,
                              hipStream_t stream) {
  const float* q = (const float*)d_in[0];
  const float* k = (const float*)d_in[1];
  const float* v = (const float*)d_in[2];
  const int* tp = (const int*)d_in[3];
  const float* rp = (const float*)d_in[4];

  float* out_msg = (float*)d_out;
  float* out_idx = out_msg + (size_t)2 * PIX * C;

  const size_t n_elem = (size_t)2 * PIX * C;
  const size_t needed = n_elem * sizeof(float) + 2 * n_elem * sizeof(__half); // 67.1 MB
  if (ws_size >= needed) {
    float* qT = (float*)d_ws;
    __half* kT = (__half*)(qT + n_elem);
    __half* vT = kT + n_elem;
    dim3 tg(PIX / 64, C / 64, 6);
    hipLaunchKernelGGL(transpose_qkv_kernel, tg, dim3(256), 0, stream,
                       q, k, v, qT, kT, vT);
    hipLaunchKernelGGL(cascade_attn_f16, dim3(2 * LBLK), dim3(256), 0, stream,
                       qT, kT, vT, tp, rp, out_msg, out_idx);
  } else {
    hipLaunchKernelGGL(cascade_attn_fallback, dim3(2 * LBLK), dim3(256), 0, stream,
                       q, k, v, tp, rp, out_msg, out_idx);
  }
}